// Round 1
// baseline (1008.322 us; speedup 1.0000x reference)
//
#include <hip/hip_runtime.h>

#define NN 20000
#define FSTRIDE 1032  // 16 rows of 1024 feats, +8 floats pad -> rows land 8 banks apart

// ---------------- B-spline basis (grid [-1,1], G=4, order 3, NB=7) ----------------
// GRID[t] = -2.5 + 0.5*t, t=0..10
__device__ __forceinline__ void bspline7(float x, float b[7]) {
  float t[10];
#pragma unroll
  for (int i = 0; i < 10; ++i) {
    float g = -2.5f + 0.5f * (float)i;
    t[i] = (x >= g && x < g + 0.5f) ? 1.0f : 0.0f;
  }
#pragma unroll
  for (int i = 0; i < 9; ++i) {  // k=1, denom 0.5
    float g = -2.5f + 0.5f * (float)i;
    t[i] = ((x - g) * t[i] + (g + 1.0f - x) * t[i + 1]) * 2.0f;
  }
#pragma unroll
  for (int i = 0; i < 8; ++i) {  // k=2, denom 1.0
    float g = -2.5f + 0.5f * (float)i;
    t[i] = ((x - g) * t[i] + (g + 1.5f - x) * t[i + 1]);
  }
#pragma unroll
  for (int i = 0; i < 7; ++i) {  // k=3, denom 1.5
    float g = -2.5f + 0.5f * (float)i;
    b[i] = ((x - g) * t[i] + (g + 2.0f - x) * t[i + 1]) * (1.0f / 1.5f);
  }
}

__device__ __forceinline__ float silu_f(float x) {
  return x * (1.0f / (1.0f + __expf(-x)));
}

// Build 16 rows x 1024 features ([silu(128) | spline(896)]) into LDS
__device__ __forceinline__ void build_features(const float* __restrict__ X, int row0, int tid,
                                               float* __restrict__ F) {
  for (int idx = tid; idx < 16 * 128; idx += 256) {
    int r = idx >> 7, i = idx & 127;
    float x = X[(size_t)(row0 + r) * 128 + i];
    float* Fr = F + r * FSTRIDE;
    Fr[i] = silu_f(x);
    float b[7];
    bspline7(x, b);
#pragma unroll
    for (int k = 0; k < 7; ++k) Fr[128 + i * 7 + k] = b[k];
  }
}

// ---------------- weight packing ----------------
// WT[f*128+o]: f<128 -> base_w[o][f], else spline_w[o][f-128]  (spline row-major (in,7) flattened)
__global__ void pack128_kernel(const float* __restrict__ Wb, const float* __restrict__ Ws,
                               float* __restrict__ WT) {
  int idx = blockIdx.x * 256 + threadIdx.x;  // 1024*128
  if (idx >= 1024 * 128) return;
  int f = idx >> 7, o = idx & 127;
  WT[(size_t)f * 128 + o] = (f < 128) ? Wb[(size_t)o * 128 + f] : Ws[(size_t)o * 896 + (f - 128)];
}

// out layer: 3 source chunks of 1024 feats each; o padded to 64 with zeros
__global__ void pack3_kernel(const float* __restrict__ Wb, const float* __restrict__ Ws,
                             float* __restrict__ WT) {
  int idx = blockIdx.x * 256 + threadIdx.x;  // 3072*64
  if (idx >= 3072 * 64) return;
  int f = idx >> 6, o = idx & 63;
  int s = f >> 10, fl = f & 1023;
  float v = 0.0f;
  if (o < 40)
    v = (fl < 128) ? Wb[(size_t)o * 384 + s * 128 + fl]
                   : Ws[(size_t)o * 2688 + s * 896 + (fl - 128)];
  WT[(size_t)f * 64 + o] = v;
}

// ---------------- graph meta: degree, scan -> CSR, dinv ----------------
__global__ void count_deg(const int* __restrict__ dst, int* __restrict__ degE, int E) {
  int e = blockIdx.x * 256 + threadIdx.x;
  if (e < E) atomicAdd(&degE[dst[e]], 1);
}

__global__ void build_meta(const int* __restrict__ degE, int* __restrict__ rowptr,
                           int* __restrict__ cursor, float* __restrict__ dinv, int n) {
  __shared__ int buf[1024];
  __shared__ int carry;
  int tid = threadIdx.x;
  if (tid == 0) { carry = 0; rowptr[0] = 0; }
  __syncthreads();
  for (int base = 0; base < n; base += 1024) {
    int i = base + tid;
    int v = (i < n) ? degE[i] : 0;
    if (i < n) dinv[i] = rsqrtf((float)(v + 1));  // +1 self loop; deg>=1 always
    buf[tid] = v;
    __syncthreads();
    for (int off = 1; off < 1024; off <<= 1) {
      int t = (tid >= off) ? buf[tid - off] : 0;
      __syncthreads();
      buf[tid] += t;
      __syncthreads();
    }
    int incl = buf[tid];
    int c = carry;
    if (i < n) {
      rowptr[i + 1] = c + incl;
      cursor[i] = c + incl - v;
    }
    __syncthreads();
    if (tid == 1023) carry = c + buf[1023];
    __syncthreads();
  }
}

__global__ void fill_csr(const int* __restrict__ src, const int* __restrict__ dst,
                         int* __restrict__ cursor, int* __restrict__ csr, int E) {
  int e = blockIdx.x * 256 + threadIdx.x;
  if (e < E) {
    int p = atomicAdd(&cursor[dst[e]], 1);
    csr[p] = src[e];
  }
}

// ---------------- KAN linear (128 in -> 128 out) ----------------
__global__ __launch_bounds__(256) void kan128_kernel(const float* __restrict__ X,
                                                     const float* __restrict__ WT,
                                                     float* __restrict__ Y) {
  __shared__ float F[16 * FSTRIDE];
  int row0 = blockIdx.x * 16;
  int tid = threadIdx.x;
  build_features(X, row0, tid, F);
  __syncthreads();
  int o0 = (tid & 31) * 4;        // 128 outs
  int rbase = (tid >> 5) * 2;     // 16 rows, 2 per thread
  const float* F0 = F + rbase * FSTRIDE;
  const float* F1 = F0 + FSTRIDE;
  float acc[2][4] = {{0.f, 0.f, 0.f, 0.f}, {0.f, 0.f, 0.f, 0.f}};
  for (int f = 0; f < 1024; f += 4) {
    float fa[4], fb[4];
    *(float4*)fa = *(const float4*)(F0 + f);
    *(float4*)fb = *(const float4*)(F1 + f);
#pragma unroll
    for (int j = 0; j < 4; ++j) {
      float w[4];
      *(float4*)w = *(const float4*)(WT + (size_t)(f + j) * 128 + o0);
#pragma unroll
      for (int q = 0; q < 4; ++q) {
        acc[0][q] += fa[j] * w[q];
        acc[1][q] += fb[j] * w[q];
      }
    }
  }
  int row = row0 + rbase;
  *(float4*)(&Y[(size_t)row * 128 + o0]) = *(float4*)acc[0];
  *(float4*)(&Y[(size_t)(row + 1) * 128 + o0]) = *(float4*)acc[1];
}

// ---------------- KAN linear output layer (384 in -> 40 out, padded 64) ----------------
__global__ __launch_bounds__(256) void kan3_kernel(const float* __restrict__ X0,
                                                   const float* __restrict__ X1,
                                                   const float* __restrict__ X2,
                                                   const float* __restrict__ WT,
                                                   float* __restrict__ Y) {
  __shared__ float F[16 * FSTRIDE];
  int row0 = blockIdx.x * 16;
  int tid = threadIdx.x;
  int o0 = (tid & 15) * 4;  // 64 outs (40 real)
  int r = tid >> 4;         // 16 rows, 1 per thread
  float acc[4] = {0.f, 0.f, 0.f, 0.f};
  const float* srcs[3] = {X0, X1, X2};
#pragma unroll 1
  for (int s = 0; s < 3; ++s) {
    __syncthreads();
    build_features(srcs[s], row0, tid, F);
    __syncthreads();
    const float* Fr = F + r * FSTRIDE;
    const float* Wc = WT + (size_t)s * 1024 * 64;
    for (int f = 0; f < 1024; f += 4) {
      float fv[4];
      *(float4*)fv = *(const float4*)(Fr + f);
#pragma unroll
      for (int j = 0; j < 4; ++j) {
        float w[4];
        *(float4*)w = *(const float4*)(Wc + (size_t)(f + j) * 64 + o0);
#pragma unroll
        for (int q = 0; q < 4; ++q) acc[q] += fv[j] * w[q];
      }
    }
  }
  if (o0 < 40) *(float4*)(&Y[(size_t)(row0 + r) * 40 + o0]) = *(float4*)acc;
}

// ---------------- aggregation: Y[n] = (H[n]*dinv[n] + sum H[s]*dinv[s]) * dinv[n] + bias ----------------
__global__ void aggregate128(const float* __restrict__ H, const int* __restrict__ rowptr,
                             const int* __restrict__ csr, const float* __restrict__ dinv,
                             const float* __restrict__ bias, float* __restrict__ Y) {
  int n = blockIdx.x;
  int f = threadIdx.x;  // 128
  float di = dinv[n];
  float acc = H[(size_t)n * 128 + f] * di;
  int e0 = rowptr[n], e1 = rowptr[n + 1];
  for (int e = e0; e < e1; ++e) {
    int s = csr[e];
    acc += H[(size_t)s * 128 + f] * dinv[s];
  }
  Y[(size_t)n * 128 + f] = acc * di + bias[f];
}

__global__ void aggregate40(const float* __restrict__ H, const int* __restrict__ rowptr,
                            const int* __restrict__ csr, const float* __restrict__ dinv,
                            const float* __restrict__ bias, float* __restrict__ Y) {
  int n = blockIdx.x;
  int f = threadIdx.x;  // 64, 40 active
  float di = dinv[n];
  float acc = (f < 40) ? H[(size_t)n * 40 + f] * di : 0.f;
  int e0 = rowptr[n], e1 = rowptr[n + 1];
  for (int e = e0; e < e1; ++e) {
    int s = csr[e];
    float ds = dinv[s];
    if (f < 40) acc += H[(size_t)s * 40 + f] * ds;
  }
  if (f < 40) Y[(size_t)n * 40 + f] = acc * di + bias[f];
}

// ---------------- batchnorm ----------------
__global__ void bn_stats(const float* __restrict__ H, double* __restrict__ stats) {
  int tid = threadIdx.x;  // 256
  int col = tid & 127;
  double s = 0.0, s2 = 0.0;
  for (size_t idx = blockIdx.x * 256 + tid; idx < (size_t)NN * 128; idx += (size_t)gridDim.x * 256) {
    float v = H[idx];
    s += v;
    s2 += (double)v * (double)v;
  }
  __shared__ double sh[512];
  sh[tid] = s;
  sh[tid + 256] = s2;
  __syncthreads();
  if (tid < 128) {
    atomicAdd(&stats[col], sh[tid] + sh[tid + 128]);
    atomicAdd(&stats[128 + col], sh[tid + 256] + sh[tid + 384]);
  }
}

__global__ void bn_final(const double* __restrict__ stats, const float* __restrict__ gamma,
                         const float* __restrict__ beta, float* __restrict__ ss) {
  int c = threadIdx.x;  // 128
  double mean = stats[c] / (double)NN;
  double var = stats[128 + c] / (double)NN - mean * mean;
  float sc = gamma[c] * rsqrtf((float)var + 1e-5f);
  ss[c] = sc;
  ss[128 + c] = beta[c] - (float)mean * sc;
}

__global__ void bn_apply(float* __restrict__ H, const float* __restrict__ ss) {
  size_t idx = (size_t)blockIdx.x * 256 + threadIdx.x;
  if (idx < (size_t)NN * 128) {
    int c = (int)(idx & 127);
    H[idx] = H[idx] * ss[c] + ss[128 + c];
  }
}

// ---------------- launch ----------------
extern "C" void kernel_launch(void* const* d_in, const int* in_sizes, int n_in,
                              void* d_out, int out_size, void* d_ws, size_t ws_size,
                              hipStream_t stream) {
  const float* x = (const float*)d_in[0];
  const int* ei = (const int*)d_in[1];
  const float* bw0 = (const float*)d_in[2];
  const float* sw0 = (const float*)d_in[3];
  const float* b0 = (const float*)d_in[4];
  const float* bw1 = (const float*)d_in[5];
  const float* sw1 = (const float*)d_in[6];
  const float* b1 = (const float*)d_in[7];
  const float* bwo = (const float*)d_in[8];
  const float* swo = (const float*)d_in[9];
  const float* bo = (const float*)d_in[10];
  const float* gamma = (const float*)d_in[11];
  const float* beta = (const float*)d_in[12];
  const int E = in_sizes[1] / 2;
  const int* esrc = ei;
  const int* edst = ei + E;

  char* ws = (char*)d_ws;
  size_t off = 0;
  auto alloc = [&](size_t bytes) -> void* {
    void* p = ws + off;
    off = (off + bytes + 255) & ~(size_t)255;
    return p;
  };
  float* WT0 = (float*)alloc(1024 * 128 * 4);
  float* WT1 = (float*)alloc(1024 * 128 * 4);
  float* WT3 = (float*)alloc(3072 * 64 * 4);
  float* dinv = (float*)alloc(NN * 4);
  int* degE = (int*)alloc(NN * 4);
  int* rowptr = (int*)alloc((NN + 1) * 4);
  int* cursor = (int*)alloc(NN * 4);
  int* csr = (int*)alloc((size_t)E * 4);
  float* A = (float*)alloc((size_t)NN * 128 * 4);
  float* h1 = (float*)alloc((size_t)NN * 128 * 4);
  float* h2 = (float*)alloc((size_t)NN * 128 * 4);
  float* C3 = (float*)alloc((size_t)NN * 40 * 4);
  double* stats = (double*)alloc(256 * 8);
  float* ss = (float*)alloc(256 * 4);
  (void)ws_size; (void)n_in; (void)out_size;

  int egrid = (E + 255) / 256;

  hipMemsetAsync(degE, 0, NN * sizeof(int), stream);
  pack128_kernel<<<512, 256, 0, stream>>>(bw0, sw0, WT0);
  pack128_kernel<<<512, 256, 0, stream>>>(bw1, sw1, WT1);
  pack3_kernel<<<768, 256, 0, stream>>>(bwo, swo, WT3);
  count_deg<<<egrid, 256, 0, stream>>>(edst, degE, E);
  build_meta<<<1, 1024, 0, stream>>>(degE, rowptr, cursor, dinv, NN);
  fill_csr<<<egrid, 256, 0, stream>>>(esrc, edst, cursor, csr, E);

  // layer 0
  kan128_kernel<<<NN / 16, 256, 0, stream>>>(x, WT0, A);
  aggregate128<<<NN, 128, 0, stream>>>(A, rowptr, csr, dinv, b0, h1);
  hipMemsetAsync(stats, 0, 256 * sizeof(double), stream);
  bn_stats<<<128, 256, 0, stream>>>(h1, stats);
  bn_final<<<1, 128, 0, stream>>>(stats, gamma, beta, ss);
  bn_apply<<<(NN * 128) / 256, 256, 0, stream>>>(h1, ss);

  // layer 1
  kan128_kernel<<<NN / 16, 256, 0, stream>>>(h1, WT1, A);
  aggregate128<<<NN, 128, 0, stream>>>(A, rowptr, csr, dinv, b1, h2);
  hipMemsetAsync(stats, 0, 256 * sizeof(double), stream);
  bn_stats<<<128, 256, 0, stream>>>(h2, stats);
  bn_final<<<1, 128, 0, stream>>>(stats, gamma, beta, ss);
  bn_apply<<<(NN * 128) / 256, 256, 0, stream>>>(h2, ss);

  // output layer
  kan3_kernel<<<NN / 16, 256, 0, stream>>>(x, h1, h2, WT3, C3);
  aggregate40<<<NN, 64, 0, stream>>>(C3, rowptr, csr, dinv, bo, (float*)d_out);
}

// Round 2
// 415.906 us; speedup vs baseline: 2.4244x; 2.4244x over previous
//
#include <hip/hip_runtime.h>

#define NN 20000

typedef _Float16 half8 __attribute__((ext_vector_type(8)));
typedef float floatx4 __attribute__((ext_vector_type(4)));

// ---------------- B-spline basis (grid [-1,1], G=4, order 3, NB=7) ----------------
__device__ __forceinline__ void bspline7(float x, float b[7]) {
  float t[10];
#pragma unroll
  for (int i = 0; i < 10; ++i) {
    float g = -2.5f + 0.5f * (float)i;
    t[i] = (x >= g && x < g + 0.5f) ? 1.0f : 0.0f;
  }
#pragma unroll
  for (int i = 0; i < 9; ++i) {  // k=1, denom 0.5
    float g = -2.5f + 0.5f * (float)i;
    t[i] = ((x - g) * t[i] + (g + 1.0f - x) * t[i + 1]) * 2.0f;
  }
#pragma unroll
  for (int i = 0; i < 8; ++i) {  // k=2, denom 1.0
    float g = -2.5f + 0.5f * (float)i;
    t[i] = ((x - g) * t[i] + (g + 1.5f - x) * t[i + 1]);
  }
#pragma unroll
  for (int i = 0; i < 7; ++i) {  // k=3, denom 1.5
    float g = -2.5f + 0.5f * (float)i;
    b[i] = ((x - g) * t[i] + (g + 2.0f - x) * t[i + 1]) * (1.0f / 1.5f);
  }
}

__device__ __forceinline__ float silu_f(float x) {
  return x * (1.0f / (1.0f + __expf(-x)));
}

// Build 32 rows x 128 inputs -> fp16 features in LDS, K interleaved as i*8+j
// ([silu, b0..b6] per input), 16B chunk index XOR-swizzled by row&7.
__device__ __forceinline__ void build_features16(const float* __restrict__ X, int row0, int tid,
                                                 _Float16* __restrict__ F) {
  for (int idx = tid; idx < 32 * 128; idx += 256) {
    int r = idx >> 7, i = idx & 127;
    float x = X[(size_t)(row0 + r) * 128 + i];
    float b[7];
    bspline7(x, b);
    half8 hv;
    hv[0] = (_Float16)silu_f(x);
#pragma unroll
    for (int k = 0; k < 7; ++k) hv[k + 1] = (_Float16)b[k];
    int chunk = i ^ (r & 7);
    *(half8*)(F + ((size_t)r * 128 + chunk) * 8) = hv;
  }
}

// ---------------- weight packing into MFMA B-fragment order (fp16) ----------------
// Layout: WP[kstep][cb][lane][jj]; value = W[k][o] with k=kstep*32+(lane>>4)*8+jj,
// o=cb*16+(lane&15); k interleaved: i=k>>3, j=k&7 (j==0 -> base, else spline[j-1]).
__global__ void packw128(const float* __restrict__ Wb, const float* __restrict__ Ws,
                         _Float16* __restrict__ WP) {
  int idx = blockIdx.x * 256 + threadIdx.x;  // 32*8*64*8 = 131072
  if (idx >= 131072) return;
  int jj = idx & 7;
  int lane = (idx >> 3) & 63;
  int cb = (idx >> 9) & 7;
  int ks = idx >> 12;
  int i = ks * 4 + (lane >> 4);
  int o = cb * 16 + (lane & 15);
  float v = (jj == 0) ? Wb[(size_t)o * 128 + i] : Ws[(size_t)o * 896 + i * 7 + (jj - 1)];
  WP[idx] = (_Float16)v;
}

// output layer: 3 chunks of K=1024, 64 cols (40 real, rest zero)
__global__ void packwout(const float* __restrict__ Wb, const float* __restrict__ Ws,
                         _Float16* __restrict__ WP) {
  int idx = blockIdx.x * 256 + threadIdx.x;  // 3*32*4*64*8 = 196608
  if (idx >= 196608) return;
  int jj = idx & 7;
  int lane = (idx >> 3) & 63;
  int cb = (idx >> 9) & 3;
  int ks = (idx >> 11) & 31;
  int s = idx >> 16;
  int i = ks * 4 + (lane >> 4);
  int o = cb * 16 + (lane & 15);
  float v = 0.0f;
  if (o < 40)
    v = (jj == 0) ? Wb[(size_t)o * 384 + s * 128 + i]
                  : Ws[(size_t)o * 2688 + s * 896 + i * 7 + (jj - 1)];
  WP[idx] = (_Float16)v;
}

// ---------------- graph meta: degree, scan -> CSR, dinv ----------------
__global__ void count_deg(const int* __restrict__ dst, int* __restrict__ degE, int E) {
  int e = blockIdx.x * 256 + threadIdx.x;
  if (e < E) atomicAdd(&degE[dst[e]], 1);
}

__global__ void build_meta(const int* __restrict__ degE, int* __restrict__ rowptr,
                           int* __restrict__ cursor, float* __restrict__ dinv, int n) {
  __shared__ int buf[1024];
  __shared__ int carry;
  int tid = threadIdx.x;
  if (tid == 0) { carry = 0; rowptr[0] = 0; }
  __syncthreads();
  for (int base = 0; base < n; base += 1024) {
    int i = base + tid;
    int v = (i < n) ? degE[i] : 0;
    if (i < n) dinv[i] = rsqrtf((float)(v + 1));  // +1 self loop
    buf[tid] = v;
    __syncthreads();
    for (int off = 1; off < 1024; off <<= 1) {
      int t = (tid >= off) ? buf[tid - off] : 0;
      __syncthreads();
      buf[tid] += t;
      __syncthreads();
    }
    int incl = buf[tid];
    int c = carry;
    if (i < n) {
      rowptr[i + 1] = c + incl;
      cursor[i] = c + incl - v;
    }
    __syncthreads();
    if (tid == 1023) carry = c + buf[1023];
    __syncthreads();
  }
}

__global__ void fill_csr(const int* __restrict__ src, const int* __restrict__ dst,
                         int* __restrict__ cursor, int* __restrict__ csr, int E) {
  int e = blockIdx.x * 256 + threadIdx.x;
  if (e < E) {
    int p = atomicAdd(&cursor[dst[e]], 1);
    csr[p] = src[e];
  }
}

// ---------------- KAN linear via MFMA (1024 -> 128), BM=32, 4 waves ----------------
__global__ __launch_bounds__(256) void kan128_mfma(const float* __restrict__ X,
                                                   const _Float16* __restrict__ WP,
                                                   float* __restrict__ Y) {
  __shared__ _Float16 F[32 * 128 * 8];  // 64 KB
  int row0 = blockIdx.x * 32;
  int tid = threadIdx.x;
  build_features16(X, row0, tid, F);
  __syncthreads();
  int lane = tid & 63, wid = tid >> 6;
  int rh = wid & 1, ch = wid >> 1;  // row half (16 rows), col half (64 cols)
  int r = rh * 16 + (lane & 15);
  int kg = lane >> 4;   // k-group 0..3
  int rx = lane & 7;    // r & 7
  const _Float16* Fr = F + (size_t)r * 128 * 8;
  floatx4 acc[4] = {};
#pragma unroll 2
  for (int ks = 0; ks < 32; ++ks) {
    half8 a = *(const half8*)(Fr + (size_t)((ks * 4 + kg) ^ rx) * 8);
    const _Float16* bp = WP + ((size_t)(ks * 8 + ch * 4) * 64 + lane) * 8;
#pragma unroll
    for (int q = 0; q < 4; ++q) {
      half8 b = *(const half8*)(bp + (size_t)q * 64 * 8);
      acc[q] = __builtin_amdgcn_mfma_f32_16x16x32_f16(a, b, acc[q], 0, 0, 0);
    }
  }
  int colb = ch * 64 + (lane & 15);
  int rowb = row0 + rh * 16 + (lane >> 4) * 4;
#pragma unroll
  for (int q = 0; q < 4; ++q)
#pragma unroll
    for (int t = 0; t < 4; ++t)
      Y[(size_t)(rowb + t) * 128 + colb + q * 16] = acc[q][t];
}

// ---------------- output KAN (3x1024 -> 40, padded 64), BM=32, 4 waves ----------------
__global__ __launch_bounds__(256) void kan3_mfma(const float* __restrict__ X0,
                                                 const float* __restrict__ X1,
                                                 const float* __restrict__ X2,
                                                 const _Float16* __restrict__ WP,
                                                 float* __restrict__ Y) {
  __shared__ _Float16 F[32 * 128 * 8];  // 64 KB
  int row0 = blockIdx.x * 32;
  int tid = threadIdx.x;
  int lane = tid & 63, wid = tid >> 6;
  int rh = wid & 1, ch = wid >> 1;  // col half: 32 cols each
  int r = rh * 16 + (lane & 15);
  int kg = lane >> 4;
  int rx = lane & 7;
  const _Float16* Fr = F + (size_t)r * 128 * 8;
  floatx4 acc[2] = {};
  const float* srcs[3] = {X0, X1, X2};
#pragma unroll 1
  for (int s = 0; s < 3; ++s) {
    if (s) __syncthreads();
    build_features16(srcs[s], row0, tid, F);
    __syncthreads();
    const _Float16* WPs = WP + (size_t)s * 32 * 4 * 64 * 8;
#pragma unroll 2
    for (int ks = 0; ks < 32; ++ks) {
      half8 a = *(const half8*)(Fr + (size_t)((ks * 4 + kg) ^ rx) * 8);
      const _Float16* bp = WPs + ((size_t)(ks * 4 + ch * 2) * 64 + lane) * 8;
#pragma unroll
      for (int q = 0; q < 2; ++q) {
        half8 b = *(const half8*)(bp + (size_t)q * 64 * 8);
        acc[q] = __builtin_amdgcn_mfma_f32_16x16x32_f16(a, b, acc[q], 0, 0, 0);
      }
    }
  }
  int rowb = row0 + rh * 16 + (lane >> 4) * 4;
#pragma unroll
  for (int q = 0; q < 2; ++q) {
    int col = ch * 32 + q * 16 + (lane & 15);
    if (col < 40)
#pragma unroll
      for (int t = 0; t < 4; ++t)
        Y[(size_t)(rowb + t) * 40 + col] = acc[q][t];
  }
}

// ---------------- aggregation ----------------
__global__ void aggregate128(const float* __restrict__ H, const int* __restrict__ rowptr,
                             const int* __restrict__ csr, const float* __restrict__ dinv,
                             const float* __restrict__ bias, float* __restrict__ Y) {
  int n = blockIdx.x;
  int f = threadIdx.x;  // 128
  float di = dinv[n];
  float acc = H[(size_t)n * 128 + f] * di;
  int e0 = rowptr[n], e1 = rowptr[n + 1];
  for (int e = e0; e < e1; ++e) {
    int s = csr[e];
    acc += H[(size_t)s * 128 + f] * dinv[s];
  }
  Y[(size_t)n * 128 + f] = acc * di + bias[f];
}

__global__ void aggregate40(const float* __restrict__ H, const int* __restrict__ rowptr,
                            const int* __restrict__ csr, const float* __restrict__ dinv,
                            const float* __restrict__ bias, float* __restrict__ Y) {
  int n = blockIdx.x;
  int f = threadIdx.x;  // 64, 40 active
  float di = dinv[n];
  float acc = (f < 40) ? H[(size_t)n * 40 + f] * di : 0.f;
  int e0 = rowptr[n], e1 = rowptr[n + 1];
  for (int e = e0; e < e1; ++e) {
    int s = csr[e];
    float ds = dinv[s];
    if (f < 40) acc += H[(size_t)s * 40 + f] * ds;
  }
  if (f < 40) Y[(size_t)n * 40 + f] = acc * di + bias[f];
}

// ---------------- batchnorm ----------------
__global__ void bn_stats(const float* __restrict__ H, double* __restrict__ stats) {
  int tid = threadIdx.x;  // 256
  int col = tid & 127;
  double s = 0.0, s2 = 0.0;
  for (size_t idx = blockIdx.x * 256 + tid; idx < (size_t)NN * 128; idx += (size_t)gridDim.x * 256) {
    float v = H[idx];
    s += v;
    s2 += (double)v * (double)v;
  }
  __shared__ double sh[512];
  sh[tid] = s;
  sh[tid + 256] = s2;
  __syncthreads();
  if (tid < 128) {
    atomicAdd(&stats[col], sh[tid] + sh[tid + 128]);
    atomicAdd(&stats[128 + col], sh[tid + 256] + sh[tid + 384]);
  }
}

__global__ void bn_final(const double* __restrict__ stats, const float* __restrict__ gamma,
                         const float* __restrict__ beta, float* __restrict__ ss) {
  int c = threadIdx.x;  // 128
  double mean = stats[c] / (double)NN;
  double var = stats[128 + c] / (double)NN - mean * mean;
  float sc = gamma[c] * rsqrtf((float)var + 1e-5f);
  ss[c] = sc;
  ss[128 + c] = beta[c] - (float)mean * sc;
}

__global__ void bn_apply(float* __restrict__ H, const float* __restrict__ ss) {
  size_t idx = (size_t)blockIdx.x * 256 + threadIdx.x;
  if (idx < (size_t)NN * 128) {
    int c = (int)(idx & 127);
    H[idx] = H[idx] * ss[c] + ss[128 + c];
  }
}

// ---------------- launch ----------------
extern "C" void kernel_launch(void* const* d_in, const int* in_sizes, int n_in,
                              void* d_out, int out_size, void* d_ws, size_t ws_size,
                              hipStream_t stream) {
  const float* x = (const float*)d_in[0];
  const int* ei = (const int*)d_in[1];
  const float* bw0 = (const float*)d_in[2];
  const float* sw0 = (const float*)d_in[3];
  const float* b0 = (const float*)d_in[4];
  const float* bw1 = (const float*)d_in[5];
  const float* sw1 = (const float*)d_in[6];
  const float* b1 = (const float*)d_in[7];
  const float* bwo = (const float*)d_in[8];
  const float* swo = (const float*)d_in[9];
  const float* bo = (const float*)d_in[10];
  const float* gamma = (const float*)d_in[11];
  const float* beta = (const float*)d_in[12];
  const int E = in_sizes[1] / 2;
  const int* esrc = ei;
  const int* edst = ei + E;

  char* ws = (char*)d_ws;
  size_t off = 0;
  auto alloc = [&](size_t bytes) -> void* {
    void* p = ws + off;
    off = (off + bytes + 255) & ~(size_t)255;
    return p;
  };
  _Float16* WP0 = (_Float16*)alloc(131072 * 2);
  _Float16* WP1 = (_Float16*)alloc(131072 * 2);
  _Float16* WPo = (_Float16*)alloc(196608 * 2);
  float* dinv = (float*)alloc(NN * 4);
  int* degE = (int*)alloc(NN * 4);
  int* rowptr = (int*)alloc((NN + 1) * 4);
  int* cursor = (int*)alloc(NN * 4);
  int* csr = (int*)alloc((size_t)E * 4);
  float* A = (float*)alloc((size_t)NN * 128 * 4);
  float* h1 = (float*)alloc((size_t)NN * 128 * 4);
  float* h2 = (float*)alloc((size_t)NN * 128 * 4);
  float* C3 = (float*)alloc((size_t)NN * 40 * 4);
  double* stats = (double*)alloc(256 * 8);
  float* ss = (float*)alloc(256 * 4);
  (void)ws_size; (void)n_in; (void)out_size;

  int egrid = (E + 255) / 256;

  hipMemsetAsync(degE, 0, NN * sizeof(int), stream);
  packw128<<<512, 256, 0, stream>>>(bw0, sw0, WP0);
  packw128<<<512, 256, 0, stream>>>(bw1, sw1, WP1);
  packwout<<<768, 256, 0, stream>>>(bwo, swo, WPo);
  count_deg<<<egrid, 256, 0, stream>>>(edst, degE, E);
  build_meta<<<1, 1024, 0, stream>>>(degE, rowptr, cursor, dinv, NN);
  fill_csr<<<egrid, 256, 0, stream>>>(esrc, edst, cursor, csr, E);

  // layer 0
  kan128_mfma<<<NN / 32, 256, 0, stream>>>(x, WP0, A);
  aggregate128<<<NN, 128, 0, stream>>>(A, rowptr, csr, dinv, b0, h1);
  hipMemsetAsync(stats, 0, 256 * sizeof(double), stream);
  bn_stats<<<128, 256, 0, stream>>>(h1, stats);
  bn_final<<<1, 128, 0, stream>>>(stats, gamma, beta, ss);
  bn_apply<<<(NN * 128) / 256, 256, 0, stream>>>(h1, ss);

  // layer 1
  kan128_mfma<<<NN / 32, 256, 0, stream>>>(h1, WP1, A);
  aggregate128<<<NN, 128, 0, stream>>>(A, rowptr, csr, dinv, b1, h2);
  hipMemsetAsync(stats, 0, 256 * sizeof(double), stream);
  bn_stats<<<128, 256, 0, stream>>>(h2, stats);
  bn_final<<<1, 128, 0, stream>>>(stats, gamma, beta, ss);
  bn_apply<<<(NN * 128) / 256, 256, 0, stream>>>(h2, ss);

  // output layer
  kan3_mfma<<<NN / 32, 256, 0, stream>>>(x, h1, h2, WPo, C3);
  aggregate40<<<NN, 64, 0, stream>>>(C3, rowptr, csr, dinv, bo, (float*)d_out);
}